// Round 3
// baseline (25.361 us; speedup 1.0000x reference)
//
#include <hip/hip_runtime.h>
#include <hip/hip_bf16.h>

#define IN_FEATURES  8192
#define OUT_FEATURES 512
#define SF           16      // IN_FEATURES / OUT_FEATURES
#define BATCH        4096
#define B_ITERS      16      // batches per thread

// out[b, o] = bias[o] + sum_{k=0..15} x[b, o*16+k] * w[o, o*16+k]
//
// 4 lanes per output element: lane j (0..3) handles x[b, o*16 + 4j .. +3].
// Wave-level x access: 64 lanes read 64 consecutive float4s = 1024 B
// contiguous -> one fully-coalesced transaction per load instruction.
// Quad reduce via 2x shfl_xor leaves the full sum in ALL 4 lanes, so for a
// group of 4 batches lane j retains the result of batch (g*4 + j) and all
// 64 lanes issue one fully-active store per group.
__global__ __launch_bounds__(256) void banded_linear_kernel(
    const float* __restrict__ x,     // [BATCH, IN_FEATURES]
    const float* __restrict__ w,     // [OUT_FEATURES, IN_FEATURES]
    const float* __restrict__ bias,  // [OUT_FEATURES]
    float* __restrict__ out)         // [BATCH, OUT_FEATURES]
{
    const int gid  = blockIdx.x * blockDim.x + threadIdx.x; // [0, 524288)
    const int j    = gid & 3;          // quarter of the 16-wide band
    const int o    = (gid >> 2) & (OUT_FEATURES - 1);
    const int slab = gid >> 11;        // [0, 256): owns 16 consecutive batches

    // weight quarter for this (o, j): row offset o*8208 floats + j*4
    const float4 wv = *reinterpret_cast<const float4*>(
        w + (size_t)o * (IN_FEATURES + SF) + (j << 2));
    const float bv = bias[o];

    const float* xbase = x + ((size_t)slab * B_ITERS << 13) + ((size_t)o << 4) + (j << 2);
    // store base for this lane: batch = slab*16 + g*4 + j, column o
    float* ob = out + (((size_t)slab * B_ITERS + j) << 9) + o;

#pragma unroll
    for (int g = 0; g < 4; ++g) {
        float res = 0.0f;
#pragma unroll
        for (int i = 0; i < 4; ++i) {
            const int b = (g << 2) + i;
            const float4 xv = *reinterpret_cast<const float4*>(xbase + ((size_t)b << 13));
            float s = fmaf(xv.x, wv.x,
                      fmaf(xv.y, wv.y,
                      fmaf(xv.z, wv.z, xv.w * wv.w)));
            // quad butterfly: full sum lands in all 4 lanes
            s += __shfl_xor(s, 1, 64);
            s += __shfl_xor(s, 2, 64);
            res = (j == i) ? s : res;   // lane j keeps batch g*4+j
        }
        __builtin_nontemporal_store(res + bv, ob + ((size_t)g << 11));
    }
}

extern "C" void kernel_launch(void* const* d_in, const int* in_sizes, int n_in,
                              void* d_out, int out_size, void* d_ws, size_t ws_size,
                              hipStream_t stream) {
    const float* x    = (const float*)d_in[0];
    const float* w    = (const float*)d_in[1];
    const float* bias = (const float*)d_in[2];
    float* out = (float*)d_out;

    // total threads = BATCH/B_ITERS * OUT_FEATURES * 4 = 256 * 512 * 4 = 524288
    const int block = 256;
    const int grid  = (BATCH / B_ITERS) * OUT_FEATURES * 4 / block;  // 2048
    banded_linear_kernel<<<grid, block, 0, stream>>>(x, w, bias, out);
}